// Round 7
// baseline (408.201 us; speedup 1.0000x reference)
//
#include <hip/hip_runtime.h>
#include <stdint.h>

// Contraction off file-wide: the uncertainty path drives top-k SELECTION ORDER
// and must be bit-identical to the JAX/numpy reference (mul+add, no fma).
// Explicit fmaf() calls (logits path) are unaffected.
#pragma clang fp contract(off)

#define NB    8
#define CCH   19
#define FCH   256
#define FIN   275
#define KP    288      // K padded to 9*32
#define NPTS  16384
#define NSAMP 49152
#define NIMP  12288
#define NRAND 4096
#define SORT_M 65536
#define CHUNK  8192
#define TP    64       // points per block in fused MFMA head
#define XROW  640      // bytes per xp row (320 bf16), 128B-multiple for swizzle
#define WBF_OFF (4u << 20)                  // bf16 weights (after keys' 4 MiB)
#define FTR_OFF (8u << 20)                  // transposed features
#define FTR_BYTES (134217728ull / 2)        // 8*16384*256*2 = 64 MiB

typedef __attribute__((ext_vector_type(8))) short bf16x8;
typedef __attribute__((ext_vector_type(4))) float f32x4;

// ---------------- threefry2x32 (exact JAX algorithm) ----------------
__host__ __device__ __forceinline__ uint32_t rotl32(uint32_t v, int r) {
  return (v << r) | (v >> (32 - r));
}

__host__ __device__ __forceinline__ void tf2x32(uint32_t k0, uint32_t k1,
                                                uint32_t x0, uint32_t x1,
                                                uint32_t* o0, uint32_t* o1) {
  const uint32_t ks2 = k0 ^ k1 ^ 0x1BD11BDAu;
  x0 += k0; x1 += k1;
#define TF_R(r) { x0 += x1; x1 = rotl32(x1, (r)); x1 ^= x0; }
  TF_R(13) TF_R(15) TF_R(26) TF_R(6)
  x0 += k1;  x1 += ks2 + 1u;
  TF_R(17) TF_R(29) TF_R(16) TF_R(24)
  x0 += ks2; x1 += k0 + 2u;
  TF_R(13) TF_R(15) TF_R(26) TF_R(6)
  x0 += k0;  x1 += k1 + 3u;
  TF_R(17) TF_R(29) TF_R(16) TF_R(24)
  x0 += k1;  x1 += ks2 + 4u;
  TF_R(13) TF_R(15) TF_R(26) TF_R(6)
  x0 += ks2; x1 += k0 + 5u;
#undef TF_R
  *o0 = x0; *o1 = x1;
}

// partitionable random_bits: bits[i] = o0 ^ o1 of tf(key, (0, i))
__device__ __forceinline__ float u01_at(uint32_t k0, uint32_t k1, uint32_t i) {
  uint32_t o0, o1;
  tf2x32(k0, k1, 0u, i, &o0, &o1);
  const uint32_t b = o0 ^ o1;
  const float f = __uint_as_float((b >> 9) | 0x3f800000u) - 1.0f;
  return fmaxf(0.0f, f);
}

__device__ __forceinline__ unsigned short f2bf(float f) {
  const uint32_t u = __float_as_uint(f);
  return (unsigned short)((u + 0x7fffu + ((u >> 16) & 1u)) >> 16);
}

__device__ __forceinline__ float bf2f(unsigned short h) {
  return __uint_as_float((uint32_t)h << 16);
}

// interp params for the LOGITS path (bf16 tolerance; same formula as exact path)
template <int SZ>
__device__ __forceinline__ void interp(float cx, float cy, int* off, float* wgt) {
  const float X = cx * (float)SZ - 0.5f, Y = cy * (float)SZ - 0.5f;
  const float x0f = floorf(X), y0f = floorf(Y);
  const float fx = X - x0f, fy = Y - y0f;
  const float wx0 = 1.0f - fx, wy0 = 1.0f - fy;
  const int x0 = (int)x0f, y0 = (int)y0f;
  const int x0c = min(max(x0, 0), SZ - 1), x1c = min(max(x0 + 1, 0), SZ - 1);
  const int y0c = min(max(y0, 0), SZ - 1), y1c = min(max(y0 + 1, 0), SZ - 1);
  const bool vx0 = (x0 >= 0) & (x0 <= SZ - 1), vx1 = (x0 >= -1) & (x0 <= SZ - 2);
  const bool vy0 = (y0 >= 0) & (y0 <= SZ - 1), vy1 = (y0 >= -1) & (y0 <= SZ - 2);
  off[0] = y0c * SZ + x0c; wgt[0] = (vy0 & vx0) ? wy0 * wx0 : 0.0f;
  off[1] = y0c * SZ + x1c; wgt[1] = (vy0 & vx1) ? wy0 * fx  : 0.0f;
  off[2] = y1c * SZ + x0c; wgt[2] = (vy1 & vx0) ? fy  * wx0 : 0.0f;
  off[3] = y1c * SZ + x1c; wgt[3] = (vy1 & vx1) ? fy  * fx  : 0.0f;
}

// ============ fusedA: transpose | unc_keys(+inline RNG) | convert_w ============
// blocks [0,8192): transpose feats (N,C,128,128) f32 -> ftr (N,16384,C) bf16
// blocks [8192,10240): uncertainty keys at candidates (RNG inline, bit-exact)
// blocks [10240,11140): weight fp32->bf16 conversion, K padded to 288
__global__ __launch_bounds__(256) void fusedA(
    const float* __restrict__ feats, unsigned short* __restrict__ ftr,
    const float* __restrict__ coarse, unsigned long long* __restrict__ keys,
    const float* __restrict__ w0, const float* __restrict__ w1,
    const float* __restrict__ w2, const float* __restrict__ wpw,
    unsigned short* __restrict__ wbf, unsigned short* __restrict__ wpb,
    uint32_t k1a, uint32_t k1b, int use_tr) {
  __shared__ unsigned short tile[64][66];   // transpose staging (bank-safe stride)
  const int bid = blockIdx.x;
  const int t = threadIdx.x;

  if (bid < 8192) {
    if (!use_tr) return;
    // ---- transpose: tile 64ch x 64px; LDS stride 66 => conflict-free ----
    const int nn = bid >> 10;
    const int ct = (bid >> 8) & 3;
    const int pt = bid & 255;
    const int c0 = ct * 64, p0 = pt * 64;
    const float* src = feats + ((size_t)nn << 22);
#pragma unroll 4
    for (int k = 0; k < 16; ++k) {
      const int c = 4 * k + (t >> 6);
      const int p = t & 63;
      tile[p][c] = f2bf(src[((size_t)(c0 + c) << 14) + p0 + p]);
    }
    __syncthreads();
    const int p = t >> 2, q = t & 3;
    const int cb = q * 16;
    uint32_t w[8];
#pragma unroll
    for (int m = 0; m < 8; ++m)
      w[m] = (uint32_t)tile[p][cb + 2 * m] | ((uint32_t)tile[p][cb + 2 * m + 1] << 16);
    unsigned short* dst = ftr + ((((size_t)nn << 14) + p0 + p) << 8) + c0 + cb;
    *(uint4*)(dst)     = make_uint4(w[0], w[1], w[2], w[3]);
    *(uint4*)(dst + 8) = make_uint4(w[4], w[5], w[6], w[7]);
  } else if (bid < 10240) {
    // ---- uncertainty -> sortable keys (EXACT path: contract-off, left-assoc) --
    const int tid = (bid - 8192) * 256 + t;
    const int nn = tid >> 16, s = tid & (SORT_M - 1);
    if (s >= NSAMP) { keys[tid] = 0xFFFFFFFFFFFFFFFFull; return; }
    const uint32_t ci = (uint32_t)(((unsigned)nn * NSAMP + (unsigned)s) * 2);
    const float cx = u01_at(k1a, k1b, ci);
    const float cy = u01_at(k1a, k1b, ci + 1);
    const float X = cx * 64.0f - 0.5f, Y = cy * 64.0f - 0.5f;
    const float x0f = floorf(X), y0f = floorf(Y);
    const float fx = X - x0f, fy = Y - y0f;
    const float wx0 = 1.0f - fx, wy0 = 1.0f - fy;
    const int x0 = (int)x0f, y0 = (int)y0f;
    const int x0c = min(max(x0, 0), 63), x1c = min(max(x0 + 1, 0), 63);
    const int y0c = min(max(y0, 0), 63), y1c = min(max(y0 + 1, 0), 63);
    const bool vx0 = (x0 >= 0) & (x0 <= 63), vx1 = (x0 >= -1) & (x0 <= 62);
    const bool vy0 = (y0 >= 0) & (y0 <= 63), vy1 = (y0 >= -1) & (y0 <= 62);
    const float w00 = (vy0 & vx0) ? wy0 * wx0 : 0.0f;
    const float w01 = (vy0 & vx1) ? wy0 * fx  : 0.0f;
    const float w10 = (vy1 & vx0) ? fy  * wx0 : 0.0f;
    const float w11 = (vy1 & vx1) ? fy  * fx  : 0.0f;
    const int o00 = y0c * 64 + x0c, o01 = y0c * 64 + x1c;
    const int o10 = y1c * 64 + x0c, o11 = y1c * 64 + x1c;
    const float* cb = coarse + (size_t)nn * (CCH * 4096);
    float m1 = -3.402823466e38f, m2 = -3.402823466e38f;
    for (int c = 0; c < CCH; ++c) {
      const float* pch = cb + (size_t)c * 4096;
      const float v = ((pch[o00] * w00 + pch[o01] * w01) + pch[o10] * w10) + pch[o11] * w11;
      if (v > m1) { m2 = m1; m1 = v; } else if (v > m2) { m2 = v; }
    }
    const float unc = m2 - m1;
    const uint32_t b = __float_as_uint(unc);
    const uint32_t asc = (b & 0x80000000u) ? ~b : (b | 0x80000000u);
    keys[tid] = ((unsigned long long)(~asc) << 32) | (uint32_t)s;
  } else {
    // ---- weight conversion ----
    const int i = (bid - 10240) * 256 + t;
    if (i < 3 * 256 * KP) {
      const int L = i / (256 * KP);
      const int rem = i - L * (256 * KP);
      const int o = rem / KP, k = rem - o * KP;
      const float* W = (L == 0) ? w0 : (L == 1) ? w1 : w2;
      wbf[i] = (k < FIN) ? f2bf(W[o * FIN + k]) : (unsigned short)0;
    } else {
      const int j = i - 3 * 256 * KP;
      const int o = j / KP, k = j - o * KP;
      wpb[j] = (o < CCH && k < FIN) ? f2bf(wpw[o * FIN + k]) : (unsigned short)0;
    }
  }
}

// ---------------- bitonic sort (per batch of 65536 u64 keys) ----------------
__global__ __launch_bounds__(1024) void bitonic_local(unsigned long long* __restrict__ keys) {
  __shared__ unsigned long long s[CHUNK];
  const int cb = blockIdx.x;
  unsigned long long* a = keys + (size_t)cb * CHUNK;
  const unsigned gbase = (unsigned)(cb * CHUNK) & (SORT_M - 1);
  for (int i = threadIdx.x; i < CHUNK; i += 1024) s[i] = a[i];
  __syncthreads();
  for (int k = 2; k <= CHUNK; k <<= 1) {
    for (int j = k >> 1; j > 0; j >>= 1) {
      for (int pid = threadIdx.x; pid < CHUNK / 2; pid += 1024) {
        const int i = ((pid & ~(j - 1)) << 1) | (pid & (j - 1));
        const int l = i | j;
        const bool up = (((gbase + i) & k) == 0);
        const unsigned long long x = s[i], y = s[l];
        if ((x > y) == up) { s[i] = y; s[l] = x; }
      }
      __syncthreads();
    }
  }
  for (int i = threadIdx.x; i < CHUNK; i += 1024) a[i] = s[i];
}

__global__ __launch_bounds__(256) void bitonic_global(unsigned long long* __restrict__ keys,
                                                      int k, int j) {
  const int t = blockIdx.x * blockDim.x + threadIdx.x;
  const int b = t >> 15, pid = t & 32767;
  const int i = ((pid & ~(j - 1)) << 1) | (pid & (j - 1));
  const int l = i | j;
  const bool up = ((i & k) == 0);
  unsigned long long* a = keys + ((size_t)b << 16);
  const unsigned long long x = a[i], y = a[l];
  if ((x > y) == up) { a[i] = y; a[l] = x; }
}

__global__ __launch_bounds__(1024) void bitonic_finish(unsigned long long* __restrict__ keys,
                                                       int k) {
  __shared__ unsigned long long s[CHUNK];
  const int cb = blockIdx.x;
  unsigned long long* a = keys + (size_t)cb * CHUNK;
  const unsigned gi0 = (unsigned)(cb * CHUNK) & (SORT_M - 1);
  for (int i = threadIdx.x; i < CHUNK; i += 1024) s[i] = a[i];
  __syncthreads();
  const bool up = ((gi0 & k) == 0);
  for (int j = CHUNK >> 1; j > 0; j >>= 1) {
    for (int pid = threadIdx.x; pid < CHUNK / 2; pid += 1024) {
      const int i = ((pid & ~(j - 1)) << 1) | (pid & (j - 1));
      const int l = i | j;
      const unsigned long long x = s[i], y = s[l];
      if ((x > y) == up) { s[i] = y; s[l] = x; }
    }
    __syncthreads();
  }
  for (int i = threadIdx.x; i < CHUNK; i += 1024) a[i] = s[i];
}

// -------- write point_coords = [imp(12288), rand(4096)] (RNG inline) --------
__global__ __launch_bounds__(256) void write_coords(const unsigned long long* __restrict__ keys,
                                                    float* __restrict__ outc,
                                                    uint32_t k1a, uint32_t k1b,
                                                    uint32_t k2a, uint32_t k2b) {
  const int t = blockIdx.x * blockDim.x + threadIdx.x;
  if (t >= NB * NPTS) return;
  const int nn = t >> 14, p = t & (NPTS - 1);
  float cx, cy;
  if (p < NIMP) {
    const unsigned idx = (unsigned)(keys[((size_t)nn << 16) + p] & 0xFFFFFFFFu);
    const uint32_t ci = ((unsigned)nn * NSAMP + idx) * 2;
    cx = u01_at(k1a, k1b, ci);
    cy = u01_at(k1a, k1b, ci + 1);
  } else {
    const uint32_t ri = ((unsigned)nn * NRAND + (unsigned)(p - NIMP)) * 2;
    cx = u01_at(k2a, k2b, ri);
    cy = u01_at(k2a, k2b, ri + 1);
  }
  outc[(size_t)t * 2] = cx;
  outc[(size_t)t * 2 + 1] = cy;
}

// ---------------- fused sample + bf16-MFMA MLP + head (512 thr) ----------------
// 64 points/block, 8 waves in a 4M x 2N grid: wave (wm=w&3, wn=w>>2) owns
// channels [64wm,64wm+64) x points [32wn,32wn+32). xp LDS only (40 KB exactly)
// with T2 XOR swizzle (byte ^= (row&7)<<4). Interp params live in registers:
// each thread serves exactly point t>>3 (TR gather) and point t&63 (c-loop).
template <int USE_TR>
__global__ __launch_bounds__(512, 6) void fused_mfma(
    const float* __restrict__ coarse, const float* __restrict__ feats,
    const unsigned short* __restrict__ ftr,
    const float* __restrict__ b0, const float* __restrict__ b1,
    const float* __restrict__ b2, const float* __restrict__ bp,
    const unsigned short* __restrict__ wbf, const unsigned short* __restrict__ wpb,
    const float* __restrict__ pc, float* __restrict__ outl) {
  __shared__ __align__(16) unsigned short xp[TP * (XROW / 2)];   // 40 KB

  const int t = threadIdx.x;
  const int nn = blockIdx.x >> 8;
  const int pbase = (blockIdx.x & 255) * TP;

  int offF[4]; float wgtF[4];     // fine interp of point t>>3
  int offC[4]; float wgtC[4];     // coarse interp of point t&63
  int offFc[4]; float wgtFc[4];   // fine interp of point t&63 (fallback only)
  {
    const float2 c = *(const float2*)(pc + ((size_t)nn * NPTS + pbase + (t >> 3)) * 2);
    interp<128>(c.x, c.y, offF, wgtF);
  }
  {
    const float2 c = *(const float2*)(pc + ((size_t)nn * NPTS + pbase + (t & 63)) * 2);
    interp<64>(c.x, c.y, offC, wgtC);
    if (!USE_TR) interp<128>(c.x, c.y, offFc, wgtFc);
  }

  if (USE_TR) {
    // ---- fine gather from transposed bf16: 8 thr/point, 32 ch each ----
    const int p = t >> 3, q = t & 7;
    const unsigned short* base = ftr + (((size_t)nn << 14) << 8) + q * 32;
    const unsigned short* n0 = base + ((size_t)offF[0] << 8);
    const unsigned short* n1 = base + ((size_t)offF[1] << 8);
    const unsigned short* n2 = base + ((size_t)offF[2] << 8);
    const unsigned short* n3 = base + ((size_t)offF[3] << 8);
    const float g0 = wgtF[0], g1 = wgtF[1], g2 = wgtF[2], g3 = wgtF[3];
    const unsigned swzp = (unsigned)(p & 7) << 4;
#pragma unroll
    for (int m = 0; m < 4; ++m) {
      const bf16x8 a = *(const bf16x8*)(n0 + m * 8);
      const bf16x8 bq = *(const bf16x8*)(n1 + m * 8);
      const bf16x8 c = *(const bf16x8*)(n2 + m * 8);
      const bf16x8 d = *(const bf16x8*)(n3 + m * 8);
      uint32_t u[4];
#pragma unroll
      for (int e = 0; e < 4; ++e) {
        float v0 = fmaf(bf2f((unsigned short)a[2 * e]), g0,
                   fmaf(bf2f((unsigned short)bq[2 * e]), g1,
                   fmaf(bf2f((unsigned short)c[2 * e]), g2,
                        bf2f((unsigned short)d[2 * e]) * g3)));
        float v1 = fmaf(bf2f((unsigned short)a[2 * e + 1]), g0,
                   fmaf(bf2f((unsigned short)bq[2 * e + 1]), g1,
                   fmaf(bf2f((unsigned short)c[2 * e + 1]), g2,
                        bf2f((unsigned short)d[2 * e + 1]) * g3)));
        u[e] = (uint32_t)f2bf(v0) | ((uint32_t)f2bf(v1) << 16);
      }
      *(uint4*)((char*)xp + p * XROW + (((unsigned)((q * 32 + m * 8) * 2)) ^ swzp)) =
          make_uint4(u[0], u[1], u[2], u[3]);
    }
  }

  // ---- remaining channels (coarse 256..274, pad 275..287; all if !USE_TR) ----
  for (int i = (USE_TR ? 8192 : 0) + t; i < (KP / 2) * TP; i += 512) {
    const int p = i & (TP - 1);   // == t & 63 (512 % 64 == 0)
    const int c0 = (i >> 6) * 2;
    float v0 = 0.0f, v1 = 0.0f;
    if (!USE_TR && c0 < FCH) {
      const float* fb0 = feats + ((size_t)nn << 22) + ((size_t)c0 << 14);
      const float* fb1 = fb0 + 16384;
      v0 = ((fb0[offFc[0]] * wgtFc[0] + fb0[offFc[1]] * wgtFc[1])
           + fb0[offFc[2]] * wgtFc[2]) + fb0[offFc[3]] * wgtFc[3];
      v1 = ((fb1[offFc[0]] * wgtFc[0] + fb1[offFc[1]] * wgtFc[1])
           + fb1[offFc[2]] * wgtFc[2]) + fb1[offFc[3]] * wgtFc[3];
    } else if (c0 >= FCH && c0 < FIN) {
      const float* cb0 = coarse + (size_t)nn * (CCH * 4096) + (size_t)(c0 - FCH) * 4096;
      v0 = ((cb0[offC[0]] * wgtC[0] + cb0[offC[1]] * wgtC[1])
           + cb0[offC[2]] * wgtC[2]) + cb0[offC[3]] * wgtC[3];
      if (c0 + 1 < FIN) {
        const float* cb1 = cb0 + 4096;
        v1 = ((cb1[offC[0]] * wgtC[0] + cb1[offC[1]] * wgtC[1])
             + cb1[offC[2]] * wgtC[2]) + cb1[offC[3]] * wgtC[3];
      }
    }
    const uint32_t u = (uint32_t)f2bf(v0) | ((uint32_t)f2bf(v1) << 16);
    *(uint32_t*)((char*)xp + p * XROW + (((unsigned)(c0 * 2)) ^ ((unsigned)(p & 7) << 4))) = u;
  }

  const int lane = t & 63, wave = t >> 6;
  const int wm = wave & 3, wn = wave >> 2;
  const int l15 = lane & 15, g = lane >> 4;
  const unsigned swz = (unsigned)(l15 & 7) << 4;
  const char* xpB = (const char*)xp;

  const float* Bs[3] = {b0, b1, b2};

  for (int L = 0; L < 3; ++L) {
    __syncthreads();   // xp inputs visible (gather for L=0, epilogue for L>0)
    const unsigned short* wL = wbf + (size_t)L * (256 * KP);
    const unsigned short* wbase = wL + (size_t)(wm * 64 + l15) * KP + g * 8;

    f32x4 acc[4][2];
#pragma unroll
    for (int mt = 0; mt < 4; ++mt)
#pragma unroll
      for (int nt = 0; nt < 2; ++nt) acc[mt][nt] = (f32x4)(0.0f);

    for (int ks = 0; ks < 9; ++ks) {
      const bf16x8 a0 = *(const bf16x8*)(wbase + 0 * 16 * KP + ks * 32);
      const bf16x8 a1 = *(const bf16x8*)(wbase + 1 * 16 * KP + ks * 32);
      const bf16x8 a2 = *(const bf16x8*)(wbase + 2 * 16 * KP + ks * 32);
      const bf16x8 a3 = *(const bf16x8*)(wbase + 3 * 16 * KP + ks * 32);
      const unsigned kb = (unsigned)(ks * 64 + g * 16) ^ swz;
      const bf16x8 q0 = *(const bf16x8*)(xpB + (wn * 32 + 0 + l15) * XROW + kb);
      const bf16x8 q1 = *(const bf16x8*)(xpB + (wn * 32 + 16 + l15) * XROW + kb);
      acc[0][0] = __builtin_amdgcn_mfma_f32_16x16x32_bf16(a0, q0, acc[0][0], 0, 0, 0);
      acc[1][0] = __builtin_amdgcn_mfma_f32_16x16x32_bf16(a1, q0, acc[1][0], 0, 0, 0);
      acc[2][0] = __builtin_amdgcn_mfma_f32_16x16x32_bf16(a2, q0, acc[2][0], 0, 0, 0);
      acc[3][0] = __builtin_amdgcn_mfma_f32_16x16x32_bf16(a3, q0, acc[3][0], 0, 0, 0);
      acc[0][1] = __builtin_amdgcn_mfma_f32_16x16x32_bf16(a0, q1, acc[0][1], 0, 0, 0);
      acc[1][1] = __builtin_amdgcn_mfma_f32_16x16x32_bf16(a1, q1, acc[1][1], 0, 0, 0);
      acc[2][1] = __builtin_amdgcn_mfma_f32_16x16x32_bf16(a2, q1, acc[2][1], 0, 0, 0);
      acc[3][1] = __builtin_amdgcn_mfma_f32_16x16x32_bf16(a3, q1, acc[3][1], 0, 0, 0);
    }
    __syncthreads();   // all reads of xp done before overwrite

    const float* __restrict__ Bv = Bs[L];
#pragma unroll
    for (int mt = 0; mt < 4; ++mt) {
      const int ch0 = wm * 64 + mt * 16 + (g << 2);
      const float4 bv = *(const float4*)(Bv + ch0);
#pragma unroll
      for (int nt = 0; nt < 2; ++nt) {
        const int p = wn * 32 + nt * 16 + l15;
        const f32x4 v = acc[mt][nt];
        const unsigned short h0 = f2bf(fmaxf(v[0] + bv.x, 0.0f));
        const unsigned short h1 = f2bf(fmaxf(v[1] + bv.y, 0.0f));
        const unsigned short h2 = f2bf(fmaxf(v[2] + bv.z, 0.0f));
        const unsigned short h3 = f2bf(fmaxf(v[3] + bv.w, 0.0f));
        uint2 u;
        u.x = (uint32_t)h0 | ((uint32_t)h1 << 16);
        u.y = (uint32_t)h2 | ((uint32_t)h3 << 16);
        *(uint2*)((char*)xp + p * XROW + (((unsigned)(ch0 * 2)) ^ swz)) = u;
      }
    }
  }
  __syncthreads();   // layer-2 output (head input) visible

  // ---- head: 8 (mt,nt) pairs, one per wave: mt = w>>2 (0..1), nt = w&3 ----
  const int hmt = wave >> 2, hnt = wave & 3;
  const unsigned short* hbase = wpb + (size_t)(hmt * 16 + l15) * KP + g * 8;
  f32x4 hacc = (f32x4)(0.0f);
  for (int ks = 0; ks < 9; ++ks) {
    const unsigned kb = (unsigned)(ks * 64 + g * 16) ^ swz;
    const bf16x8 ha = *(const bf16x8*)(hbase + ks * 32);
    const bf16x8 hb = *(const bf16x8*)(xpB + (hnt * 16 + l15) * XROW + kb);
    hacc = __builtin_amdgcn_mfma_f32_16x16x32_bf16(ha, hb, hacc, 0, 0, 0);
  }
  const int p = pbase + hnt * 16 + l15;
#pragma unroll
  for (int j = 0; j < 4; ++j) {
    const int ch = hmt * 16 + (g << 2) + j;
    if (ch < CCH)
      outl[((size_t)nn * CCH + ch) * NPTS + p] = hacc[j] + bp[ch];
  }
}

// ---------------- launcher ----------------
extern "C" void kernel_launch(void* const* d_in, const int* in_sizes, int n_in,
                              void* d_out, int out_size, void* d_ws, size_t ws_size,
                              hipStream_t stream) {
  const float* coarse = (const float*)d_in[0];
  const float* feats  = (const float*)d_in[1];
  const float* w0 = (const float*)d_in[2]; const float* b0 = (const float*)d_in[3];
  const float* w1 = (const float*)d_in[4]; const float* b1 = (const float*)d_in[5];
  const float* w2 = (const float*)d_in[6]; const float* b2 = (const float*)d_in[7];
  const float* wp = (const float*)d_in[8]; const float* bp = (const float*)d_in[9];

  float* out0 = (float*)d_out;
  float* outL = out0 + 622592;
  float* outC = outL + 2490368;

  unsigned long long* keys = (unsigned long long*)d_ws;            // 4 MiB
  unsigned short* wbf = (unsigned short*)((char*)d_ws + WBF_OFF);  // 432 KiB
  unsigned short* wpb = wbf + 3 * 256 * KP;
  unsigned short* ftr = (unsigned short*)((char*)d_ws + FTR_OFF);  // 64 MiB
  const int use_tr = (ws_size >= (size_t)FTR_OFF + FTR_BYTES) ? 1 : 0;

  // host-side split of jax.random.key(7) = (0,7): key_i = tf(key, (0,i))
  uint32_t k1a, k1b, k2a, k2b;
  tf2x32(0u, 7u, 0u, 0u, &k1a, &k1b);
  tf2x32(0u, 7u, 0u, 1u, &k2a, &k2b);

  hipMemcpyAsync(out0, coarse, 622592 * sizeof(float),
                 hipMemcpyDeviceToDevice, stream);

  // transpose || uncertainty+RNG || weight-convert in one dispatch
  fusedA<<<11140, 256, 0, stream>>>(feats, ftr, coarse, keys,
                                    w0, w1, w2, wp, wbf, wpb, k1a, k1b, use_tr);

  bitonic_local<<<64, 1024, 0, stream>>>(keys);
  bitonic_global<<<1024, 256, 0, stream>>>(keys, 16384, 8192);
  bitonic_finish<<<64, 1024, 0, stream>>>(keys, 16384);
  bitonic_global<<<1024, 256, 0, stream>>>(keys, 32768, 16384);
  bitonic_global<<<1024, 256, 0, stream>>>(keys, 32768, 8192);
  bitonic_finish<<<64, 1024, 0, stream>>>(keys, 32768);
  bitonic_global<<<1024, 256, 0, stream>>>(keys, 65536, 32768);
  bitonic_global<<<1024, 256, 0, stream>>>(keys, 65536, 16384);
  bitonic_global<<<1024, 256, 0, stream>>>(keys, 65536, 8192);
  bitonic_finish<<<64, 1024, 0, stream>>>(keys, 65536);

  write_coords<<<512, 256, 0, stream>>>(keys, outC, k1a, k1b, k2a, k2b);

  if (use_tr)
    fused_mfma<1><<<2048, 512, 0, stream>>>(coarse, feats, ftr, b0, b1, b2, bp,
                                            wbf, wpb, outC, outL);
  else
    fused_mfma<0><<<2048, 512, 0, stream>>>(coarse, feats, ftr, b0, b1, b2, bp,
                                            wbf, wpb, outC, outL);
}

// Round 8
// 389.291 us; speedup vs baseline: 1.0486x; 1.0486x over previous
//
#include <hip/hip_runtime.h>
#include <stdint.h>

// Contraction off file-wide: the uncertainty path drives top-k SELECTION ORDER
// and must be bit-identical to the JAX/numpy reference (mul+add, no fma).
// Explicit fmaf() calls (logits path) are unaffected.
#pragma clang fp contract(off)

#define NB    8
#define CCH   19
#define FCH   256
#define FIN   275
#define KP    288      // K padded to 9*32
#define NPTS  16384
#define NSAMP 49152
#define NIMP  12288
#define NRAND 4096
#define SORT_M 65536
#define CHUNK  8192
#define TP    64       // points per block in fused MFMA head
#define XROW  640      // bytes per xp row (320 bf16), 128B-multiple for swizzle
#define WBF_OFF (4u << 20)                  // bf16 weights (after keys' 4 MiB)
#define FTR_OFF (8u << 20)                  // transposed features
#define FTR_BYTES (134217728ull / 2)        // 8*16384*256*2 = 64 MiB

typedef __attribute__((ext_vector_type(8))) short bf16x8;
typedef __attribute__((ext_vector_type(4))) float f32x4;

// ---------------- threefry2x32 (exact JAX algorithm) ----------------
__host__ __device__ __forceinline__ uint32_t rotl32(uint32_t v, int r) {
  return (v << r) | (v >> (32 - r));
}

__host__ __device__ __forceinline__ void tf2x32(uint32_t k0, uint32_t k1,
                                                uint32_t x0, uint32_t x1,
                                                uint32_t* o0, uint32_t* o1) {
  const uint32_t ks2 = k0 ^ k1 ^ 0x1BD11BDAu;
  x0 += k0; x1 += k1;
#define TF_R(r) { x0 += x1; x1 = rotl32(x1, (r)); x1 ^= x0; }
  TF_R(13) TF_R(15) TF_R(26) TF_R(6)
  x0 += k1;  x1 += ks2 + 1u;
  TF_R(17) TF_R(29) TF_R(16) TF_R(24)
  x0 += ks2; x1 += k0 + 2u;
  TF_R(13) TF_R(15) TF_R(26) TF_R(6)
  x0 += k0;  x1 += k1 + 3u;
  TF_R(17) TF_R(29) TF_R(16) TF_R(24)
  x0 += k1;  x1 += ks2 + 4u;
  TF_R(13) TF_R(15) TF_R(26) TF_R(6)
  x0 += ks2; x1 += k0 + 5u;
#undef TF_R
  *o0 = x0; *o1 = x1;
}

// partitionable random_bits: bits[i] = o0 ^ o1 of tf(key, (0, i))
__device__ __forceinline__ float u01_at(uint32_t k0, uint32_t k1, uint32_t i) {
  uint32_t o0, o1;
  tf2x32(k0, k1, 0u, i, &o0, &o1);
  const uint32_t b = o0 ^ o1;
  const float f = __uint_as_float((b >> 9) | 0x3f800000u) - 1.0f;
  return fmaxf(0.0f, f);
}

__device__ __forceinline__ unsigned short f2bf(float f) {
  const uint32_t u = __float_as_uint(f);
  return (unsigned short)((u + 0x7fffu + ((u >> 16) & 1u)) >> 16);
}

__device__ __forceinline__ float bf2f(unsigned short h) {
  return __uint_as_float((uint32_t)h << 16);
}

// interp params for the LOGITS path (bf16 tolerance; same formula as exact path)
template <int SZ>
__device__ __forceinline__ void interp(float cx, float cy, int* off, float* wgt) {
  const float X = cx * (float)SZ - 0.5f, Y = cy * (float)SZ - 0.5f;
  const float x0f = floorf(X), y0f = floorf(Y);
  const float fx = X - x0f, fy = Y - y0f;
  const float wx0 = 1.0f - fx, wy0 = 1.0f - fy;
  const int x0 = (int)x0f, y0 = (int)y0f;
  const int x0c = min(max(x0, 0), SZ - 1), x1c = min(max(x0 + 1, 0), SZ - 1);
  const int y0c = min(max(y0, 0), SZ - 1), y1c = min(max(y0 + 1, 0), SZ - 1);
  const bool vx0 = (x0 >= 0) & (x0 <= SZ - 1), vx1 = (x0 >= -1) & (x0 <= SZ - 2);
  const bool vy0 = (y0 >= 0) & (y0 <= SZ - 1), vy1 = (y0 >= -1) & (y0 <= SZ - 2);
  off[0] = y0c * SZ + x0c; wgt[0] = (vy0 & vx0) ? wy0 * wx0 : 0.0f;
  off[1] = y0c * SZ + x1c; wgt[1] = (vy0 & vx1) ? wy0 * fx  : 0.0f;
  off[2] = y1c * SZ + x0c; wgt[2] = (vy1 & vx0) ? fy  * wx0 : 0.0f;
  off[3] = y1c * SZ + x1c; wgt[3] = (vy1 & vx1) ? fy  * fx  : 0.0f;
}

// ============ fusedA: transpose | unc_keys(+inline RNG) | convert_w ============
// blocks [0,8192): transpose feats (N,C,128,128) f32 -> ftr (N,16384,C) bf16
// blocks [8192,10240): uncertainty keys at candidates (RNG inline, bit-exact)
// blocks [10240,11140): weight fp32->bf16 conversion, K padded to 288
__global__ __launch_bounds__(256) void fusedA(
    const float* __restrict__ feats, unsigned short* __restrict__ ftr,
    const float* __restrict__ coarse, unsigned long long* __restrict__ keys,
    const float* __restrict__ w0, const float* __restrict__ w1,
    const float* __restrict__ w2, const float* __restrict__ wpw,
    unsigned short* __restrict__ wbf, unsigned short* __restrict__ wpb,
    uint32_t k1a, uint32_t k1b, int use_tr) {
  __shared__ unsigned short tile[64][66];   // transpose staging (bank-safe stride)
  const int bid = blockIdx.x;
  const int t = threadIdx.x;

  if (bid < 8192) {
    if (!use_tr) return;
    // ---- transpose: tile 64ch x 64px; LDS stride 66 => conflict-free ----
    const int nn = bid >> 10;
    const int ct = (bid >> 8) & 3;
    const int pt = bid & 255;
    const int c0 = ct * 64, p0 = pt * 64;
    const float* src = feats + ((size_t)nn << 22);
#pragma unroll 4
    for (int k = 0; k < 16; ++k) {
      const int c = 4 * k + (t >> 6);
      const int p = t & 63;
      tile[p][c] = f2bf(src[((size_t)(c0 + c) << 14) + p0 + p]);
    }
    __syncthreads();
    const int p = t >> 2, q = t & 3;
    const int cb = q * 16;
    uint32_t w[8];
#pragma unroll
    for (int m = 0; m < 8; ++m)
      w[m] = (uint32_t)tile[p][cb + 2 * m] | ((uint32_t)tile[p][cb + 2 * m + 1] << 16);
    unsigned short* dst = ftr + ((((size_t)nn << 14) + p0 + p) << 8) + c0 + cb;
    *(uint4*)(dst)     = make_uint4(w[0], w[1], w[2], w[3]);
    *(uint4*)(dst + 8) = make_uint4(w[4], w[5], w[6], w[7]);
  } else if (bid < 10240) {
    // ---- uncertainty -> sortable keys (EXACT path: contract-off, left-assoc) --
    const int tid = (bid - 8192) * 256 + t;
    const int nn = tid >> 16, s = tid & (SORT_M - 1);
    if (s >= NSAMP) { keys[tid] = 0xFFFFFFFFFFFFFFFFull; return; }
    const uint32_t ci = (uint32_t)(((unsigned)nn * NSAMP + (unsigned)s) * 2);
    const float cx = u01_at(k1a, k1b, ci);
    const float cy = u01_at(k1a, k1b, ci + 1);
    const float X = cx * 64.0f - 0.5f, Y = cy * 64.0f - 0.5f;
    const float x0f = floorf(X), y0f = floorf(Y);
    const float fx = X - x0f, fy = Y - y0f;
    const float wx0 = 1.0f - fx, wy0 = 1.0f - fy;
    const int x0 = (int)x0f, y0 = (int)y0f;
    const int x0c = min(max(x0, 0), 63), x1c = min(max(x0 + 1, 0), 63);
    const int y0c = min(max(y0, 0), 63), y1c = min(max(y0 + 1, 0), 63);
    const bool vx0 = (x0 >= 0) & (x0 <= 63), vx1 = (x0 >= -1) & (x0 <= 62);
    const bool vy0 = (y0 >= 0) & (y0 <= 63), vy1 = (y0 >= -1) & (y0 <= 62);
    const float w00 = (vy0 & vx0) ? wy0 * wx0 : 0.0f;
    const float w01 = (vy0 & vx1) ? wy0 * fx  : 0.0f;
    const float w10 = (vy1 & vx0) ? fy  * wx0 : 0.0f;
    const float w11 = (vy1 & vx1) ? fy  * fx  : 0.0f;
    const int o00 = y0c * 64 + x0c, o01 = y0c * 64 + x1c;
    const int o10 = y1c * 64 + x0c, o11 = y1c * 64 + x1c;
    const float* cb = coarse + (size_t)nn * (CCH * 4096);
    float m1 = -3.402823466e38f, m2 = -3.402823466e38f;
    for (int c = 0; c < CCH; ++c) {
      const float* pch = cb + (size_t)c * 4096;
      const float v = ((pch[o00] * w00 + pch[o01] * w01) + pch[o10] * w10) + pch[o11] * w11;
      if (v > m1) { m2 = m1; m1 = v; } else if (v > m2) { m2 = v; }
    }
    const float unc = m2 - m1;
    const uint32_t b = __float_as_uint(unc);
    const uint32_t asc = (b & 0x80000000u) ? ~b : (b | 0x80000000u);
    keys[tid] = ((unsigned long long)(~asc) << 32) | (uint32_t)s;
  } else {
    // ---- weight conversion ----
    const int i = (bid - 10240) * 256 + t;
    if (i < 3 * 256 * KP) {
      const int L = i / (256 * KP);
      const int rem = i - L * (256 * KP);
      const int o = rem / KP, k = rem - o * KP;
      const float* W = (L == 0) ? w0 : (L == 1) ? w1 : w2;
      wbf[i] = (k < FIN) ? f2bf(W[o * FIN + k]) : (unsigned short)0;
    } else {
      const int j = i - 3 * 256 * KP;
      const int o = j / KP, k = j - o * KP;
      wpb[j] = (o < CCH && k < FIN) ? f2bf(wpw[o * FIN + k]) : (unsigned short)0;
    }
  }
}

// ---------------- bitonic sort (per batch of 65536 u64 keys) ----------------
__global__ __launch_bounds__(1024) void bitonic_local(unsigned long long* __restrict__ keys) {
  __shared__ unsigned long long s[CHUNK];
  const int cb = blockIdx.x;
  unsigned long long* a = keys + (size_t)cb * CHUNK;
  const unsigned gbase = (unsigned)(cb * CHUNK) & (SORT_M - 1);
  for (int i = threadIdx.x; i < CHUNK; i += 1024) s[i] = a[i];
  __syncthreads();
  for (int k = 2; k <= CHUNK; k <<= 1) {
    for (int j = k >> 1; j > 0; j >>= 1) {
      for (int pid = threadIdx.x; pid < CHUNK / 2; pid += 1024) {
        const int i = ((pid & ~(j - 1)) << 1) | (pid & (j - 1));
        const int l = i | j;
        const bool up = (((gbase + i) & k) == 0);
        const unsigned long long x = s[i], y = s[l];
        if ((x > y) == up) { s[i] = y; s[l] = x; }
      }
      __syncthreads();
    }
  }
  for (int i = threadIdx.x; i < CHUNK; i += 1024) a[i] = s[i];
}

// global compare-exchange; ppb_shift = log2(pairs per batch). Restricting the
// pair count restricts coverage to the lowest 2*npairs elements of each batch
// (used for the k=65536 tail where only the lowest 16K matter).
__global__ __launch_bounds__(256) void bitonic_global(unsigned long long* __restrict__ keys,
                                                      int k, int j, int ppb_shift) {
  const int t = blockIdx.x * blockDim.x + threadIdx.x;
  const int b = t >> ppb_shift, pid = t & ((1 << ppb_shift) - 1);
  const int i = ((pid & ~(j - 1)) << 1) | (pid & (j - 1));
  const int l = i | j;
  const bool up = ((i & k) == 0);
  unsigned long long* a = keys + ((size_t)b << 16);
  const unsigned long long x = a[i], y = a[l];
  if ((x > y) == up) { a[i] = y; a[l] = x; }
}

__global__ __launch_bounds__(1024) void bitonic_finish(unsigned long long* __restrict__ keys,
                                                       int k) {
  __shared__ unsigned long long s[CHUNK];
  const int cb = blockIdx.x;
  unsigned long long* a = keys + (size_t)cb * CHUNK;
  const unsigned gi0 = (unsigned)(cb * CHUNK) & (SORT_M - 1);
  for (int i = threadIdx.x; i < CHUNK; i += 1024) s[i] = a[i];
  __syncthreads();
  const bool up = ((gi0 & k) == 0);
  for (int j = CHUNK >> 1; j > 0; j >>= 1) {
    for (int pid = threadIdx.x; pid < CHUNK / 2; pid += 1024) {
      const int i = ((pid & ~(j - 1)) << 1) | (pid & (j - 1));
      const int l = i | j;
      const unsigned long long x = s[i], y = s[l];
      if ((x > y) == up) { s[i] = y; s[l] = x; }
    }
    __syncthreads();
  }
  for (int i = threadIdx.x; i < CHUNK; i += 1024) a[i] = s[i];
}

// ---- final: finish j<=4096 (ascending) on the lowest-16K chunks of each
// batch, then write point_coords DIRECTLY from the sorted LDS keys (RNG
// inline). Chunk 0 -> positions 0..8191 (all imp); chunk 1 -> 8192..16383
// (imp 8192..12287 + all 4096 rand). Keys are not written back (unused). ----
__global__ __launch_bounds__(1024) void finlow_coords(
    const unsigned long long* __restrict__ keys, float* __restrict__ outc,
    uint32_t k1a, uint32_t k1b, uint32_t k2a, uint32_t k2b) {
  __shared__ unsigned long long s[CHUNK];
  const int nn = blockIdx.x >> 1, half = blockIdx.x & 1;
  const unsigned long long* a = keys + ((size_t)nn << 16) + half * CHUNK;
  for (int i = threadIdx.x; i < CHUNK; i += 1024) s[i] = a[i];
  __syncthreads();
  for (int j = CHUNK >> 1; j > 0; j >>= 1) {   // ascending (i & 65536 == 0)
    for (int pid = threadIdx.x; pid < CHUNK / 2; pid += 1024) {
      const int i = ((pid & ~(j - 1)) << 1) | (pid & (j - 1));
      const int l = i | j;
      const unsigned long long x = s[i], y = s[l];
      if (x > y) { s[i] = y; s[l] = x; }
    }
    __syncthreads();
  }
  const int pb = half * CHUNK;
  for (int q = threadIdx.x; q < CHUNK; q += 1024) {
    const int p = pb + q;
    float cx, cy;
    if (p < NIMP) {
      const unsigned idx = (unsigned)(s[q] & 0xFFFFFFFFu);
      const uint32_t ci = ((unsigned)nn * NSAMP + idx) * 2;
      cx = u01_at(k1a, k1b, ci);
      cy = u01_at(k1a, k1b, ci + 1);
    } else {
      const uint32_t ri = ((unsigned)nn * NRAND + (unsigned)(p - NIMP)) * 2;
      cx = u01_at(k2a, k2b, ri);
      cy = u01_at(k2a, k2b, ri + 1);
    }
    float* o = outc + (((size_t)nn << 14) + p) * 2;
    o[0] = cx; o[1] = cy;
  }
}

// ---------------- fused sample + bf16-MFMA MLP + head (512 thr) ----------------
// 64 points/block, 8 waves in a 4M x 2N grid. xp LDS only (40 KB) with T2 XOR
// swizzle (byte ^= (row&7)<<4). launch_bounds(512,4): 128-VGPR budget — the
// (512,6) variant forced 40 VGPRs and spilled ~88 MB to scratch (r7 WRITE_SIZE).
template <int USE_TR>
__global__ __launch_bounds__(512, 4) void fused_mfma(
    const float* __restrict__ coarse, const float* __restrict__ feats,
    const unsigned short* __restrict__ ftr,
    const float* __restrict__ b0, const float* __restrict__ b1,
    const float* __restrict__ b2, const float* __restrict__ bp,
    const unsigned short* __restrict__ wbf, const unsigned short* __restrict__ wpb,
    const float* __restrict__ pc, float* __restrict__ outl) {
  __shared__ __align__(16) unsigned short xp[TP * (XROW / 2)];   // 40 KB

  const int t = threadIdx.x;
  const int nn = blockIdx.x >> 8;
  const int pbase = (blockIdx.x & 255) * TP;

  int offF[4]; float wgtF[4];     // fine interp of point t>>3
  int offC[4]; float wgtC[4];     // coarse interp of point t&63
  int offFc[4]; float wgtFc[4];   // fine interp of point t&63 (fallback only)
  {
    const float2 c = *(const float2*)(pc + ((size_t)nn * NPTS + pbase + (t >> 3)) * 2);
    interp<128>(c.x, c.y, offF, wgtF);
  }
  {
    const float2 c = *(const float2*)(pc + ((size_t)nn * NPTS + pbase + (t & 63)) * 2);
    interp<64>(c.x, c.y, offC, wgtC);
    if (!USE_TR) interp<128>(c.x, c.y, offFc, wgtFc);
  }

  if (USE_TR) {
    // ---- fine gather from transposed bf16: 8 thr/point, 32 ch each ----
    const int p = t >> 3, q = t & 7;
    const unsigned short* base = ftr + (((size_t)nn << 14) << 8) + q * 32;
    const unsigned short* n0 = base + ((size_t)offF[0] << 8);
    const unsigned short* n1 = base + ((size_t)offF[1] << 8);
    const unsigned short* n2 = base + ((size_t)offF[2] << 8);
    const unsigned short* n3 = base + ((size_t)offF[3] << 8);
    const float g0 = wgtF[0], g1 = wgtF[1], g2 = wgtF[2], g3 = wgtF[3];
    const unsigned swzp = (unsigned)(p & 7) << 4;
#pragma unroll
    for (int m = 0; m < 4; ++m) {
      const bf16x8 a = *(const bf16x8*)(n0 + m * 8);
      const bf16x8 bq = *(const bf16x8*)(n1 + m * 8);
      const bf16x8 c = *(const bf16x8*)(n2 + m * 8);
      const bf16x8 d = *(const bf16x8*)(n3 + m * 8);
      uint32_t u[4];
#pragma unroll
      for (int e = 0; e < 4; ++e) {
        float v0 = fmaf(bf2f((unsigned short)a[2 * e]), g0,
                   fmaf(bf2f((unsigned short)bq[2 * e]), g1,
                   fmaf(bf2f((unsigned short)c[2 * e]), g2,
                        bf2f((unsigned short)d[2 * e]) * g3)));
        float v1 = fmaf(bf2f((unsigned short)a[2 * e + 1]), g0,
                   fmaf(bf2f((unsigned short)bq[2 * e + 1]), g1,
                   fmaf(bf2f((unsigned short)c[2 * e + 1]), g2,
                        bf2f((unsigned short)d[2 * e + 1]) * g3)));
        u[e] = (uint32_t)f2bf(v0) | ((uint32_t)f2bf(v1) << 16);
      }
      *(uint4*)((char*)xp + p * XROW + (((unsigned)((q * 32 + m * 8) * 2)) ^ swzp)) =
          make_uint4(u[0], u[1], u[2], u[3]);
    }
  }

  // ---- remaining channels (coarse 256..274, pad 275..287; all if !USE_TR) ----
  for (int i = (USE_TR ? 8192 : 0) + t; i < (KP / 2) * TP; i += 512) {
    const int p = i & (TP - 1);   // == t & 63 (512 % 64 == 0)
    const int c0 = (i >> 6) * 2;
    float v0 = 0.0f, v1 = 0.0f;
    if (!USE_TR && c0 < FCH) {
      const float* fb0 = feats + ((size_t)nn << 22) + ((size_t)c0 << 14);
      const float* fb1 = fb0 + 16384;
      v0 = ((fb0[offFc[0]] * wgtFc[0] + fb0[offFc[1]] * wgtFc[1])
           + fb0[offFc[2]] * wgtFc[2]) + fb0[offFc[3]] * wgtFc[3];
      v1 = ((fb1[offFc[0]] * wgtFc[0] + fb1[offFc[1]] * wgtFc[1])
           + fb1[offFc[2]] * wgtFc[2]) + fb1[offFc[3]] * wgtFc[3];
    } else if (c0 >= FCH && c0 < FIN) {
      const float* cb0 = coarse + (size_t)nn * (CCH * 4096) + (size_t)(c0 - FCH) * 4096;
      v0 = ((cb0[offC[0]] * wgtC[0] + cb0[offC[1]] * wgtC[1])
           + cb0[offC[2]] * wgtC[2]) + cb0[offC[3]] * wgtC[3];
      if (c0 + 1 < FIN) {
        const float* cb1 = cb0 + 4096;
        v1 = ((cb1[offC[0]] * wgtC[0] + cb1[offC[1]] * wgtC[1])
             + cb1[offC[2]] * wgtC[2]) + cb1[offC[3]] * wgtC[3];
      }
    }
    const uint32_t u = (uint32_t)f2bf(v0) | ((uint32_t)f2bf(v1) << 16);
    *(uint32_t*)((char*)xp + p * XROW + (((unsigned)(c0 * 2)) ^ ((unsigned)(p & 7) << 4))) = u;
  }

  const int lane = t & 63, wave = t >> 6;
  const int wm = wave & 3, wn = wave >> 2;
  const int l15 = lane & 15, g = lane >> 4;
  const unsigned swz = (unsigned)(l15 & 7) << 4;
  const char* xpB = (const char*)xp;

#pragma unroll    // static L => Bs/wL fully resolved, no runtime-indexed arrays
  for (int L = 0; L < 3; ++L) {
    __syncthreads();   // xp inputs visible (gather for L=0, epilogue for L>0)
    const float* Bv = (L == 0) ? b0 : (L == 1) ? b1 : b2;
    const unsigned short* wL = wbf + (size_t)L * (256 * KP);
    const unsigned short* wbase = wL + (size_t)(wm * 64 + l15) * KP + g * 8;

    f32x4 acc[4][2];
#pragma unroll
    for (int mt = 0; mt < 4; ++mt)
#pragma unroll
      for (int nt = 0; nt < 2; ++nt) acc[mt][nt] = (f32x4)(0.0f);

    for (int ks = 0; ks < 9; ++ks) {
      const bf16x8 a0 = *(const bf16x8*)(wbase + 0 * 16 * KP + ks * 32);
      const bf16x8 a1 = *(const bf16x8*)(wbase + 1 * 16 * KP + ks * 32);
      const bf16x8 a2 = *(const bf16x8*)(wbase + 2 * 16 * KP + ks * 32);
      const bf16x8 a3 = *(const bf16x8*)(wbase + 3 * 16 * KP + ks * 32);
      const unsigned kb = (unsigned)(ks * 64 + g * 16) ^ swz;
      const bf16x8 q0 = *(const bf16x8*)(xpB + (wn * 32 + 0 + l15) * XROW + kb);
      const bf16x8 q1 = *(const bf16x8*)(xpB + (wn * 32 + 16 + l15) * XROW + kb);
      acc[0][0] = __builtin_amdgcn_mfma_f32_16x16x32_bf16(a0, q0, acc[0][0], 0, 0, 0);
      acc[1][0] = __builtin_amdgcn_mfma_f32_16x16x32_bf16(a1, q0, acc[1][0], 0, 0, 0);
      acc[2][0] = __builtin_amdgcn_mfma_f32_16x16x32_bf16(a2, q0, acc[2][0], 0, 0, 0);
      acc[3][0] = __builtin_amdgcn_mfma_f32_16x16x32_bf16(a3, q0, acc[3][0], 0, 0, 0);
      acc[0][1] = __builtin_amdgcn_mfma_f32_16x16x32_bf16(a0, q1, acc[0][1], 0, 0, 0);
      acc[1][1] = __builtin_amdgcn_mfma_f32_16x16x32_bf16(a1, q1, acc[1][1], 0, 0, 0);
      acc[2][1] = __builtin_amdgcn_mfma_f32_16x16x32_bf16(a2, q1, acc[2][1], 0, 0, 0);
      acc[3][1] = __builtin_amdgcn_mfma_f32_16x16x32_bf16(a3, q1, acc[3][1], 0, 0, 0);
    }
    __syncthreads();   // all reads of xp done before overwrite

#pragma unroll
    for (int mt = 0; mt < 4; ++mt) {
      const int ch0 = wm * 64 + mt * 16 + (g << 2);
      const float4 bv = *(const float4*)(Bv + ch0);
#pragma unroll
      for (int nt = 0; nt < 2; ++nt) {
        const int p = wn * 32 + nt * 16 + l15;
        const f32x4 v = acc[mt][nt];
        const unsigned short h0 = f2bf(fmaxf(v[0] + bv.x, 0.0f));
        const unsigned short h1 = f2bf(fmaxf(v[1] + bv.y, 0.0f));
        const unsigned short h2 = f2bf(fmaxf(v[2] + bv.z, 0.0f));
        const unsigned short h3 = f2bf(fmaxf(v[3] + bv.w, 0.0f));
        uint2 u;
        u.x = (uint32_t)h0 | ((uint32_t)h1 << 16);
        u.y = (uint32_t)h2 | ((uint32_t)h3 << 16);
        *(uint2*)((char*)xp + p * XROW + (((unsigned)(ch0 * 2)) ^ swz)) = u;
      }
    }
  }
  __syncthreads();   // layer-2 output (head input) visible

  // ---- head: 8 (mt,nt) pairs, one per wave: mt = w>>2 (0..1), nt = w&3 ----
  const int hmt = wave >> 2, hnt = wave & 3;
  const unsigned short* hbase = wpb + (size_t)(hmt * 16 + l15) * KP + g * 8;
  f32x4 hacc = (f32x4)(0.0f);
  for (int ks = 0; ks < 9; ++ks) {
    const unsigned kb = (unsigned)(ks * 64 + g * 16) ^ swz;
    const bf16x8 ha = *(const bf16x8*)(hbase + ks * 32);
    const bf16x8 hb = *(const bf16x8*)(xpB + (hnt * 16 + l15) * XROW + kb);
    hacc = __builtin_amdgcn_mfma_f32_16x16x32_bf16(ha, hb, hacc, 0, 0, 0);
  }
  const int p = pbase + hnt * 16 + l15;
#pragma unroll
  for (int j = 0; j < 4; ++j) {
    const int ch = hmt * 16 + (g << 2) + j;
    if (ch < CCH)
      outl[((size_t)nn * CCH + ch) * NPTS + p] = hacc[j] + bp[ch];
  }
}

// ---------------- launcher ----------------
extern "C" void kernel_launch(void* const* d_in, const int* in_sizes, int n_in,
                              void* d_out, int out_size, void* d_ws, size_t ws_size,
                              hipStream_t stream) {
  const float* coarse = (const float*)d_in[0];
  const float* feats  = (const float*)d_in[1];
  const float* w0 = (const float*)d_in[2]; const float* b0 = (const float*)d_in[3];
  const float* w1 = (const float*)d_in[4]; const float* b1 = (const float*)d_in[5];
  const float* w2 = (const float*)d_in[6]; const float* b2 = (const float*)d_in[7];
  const float* wp = (const float*)d_in[8]; const float* bp = (const float*)d_in[9];

  float* out0 = (float*)d_out;
  float* outL = out0 + 622592;
  float* outC = outL + 2490368;

  unsigned long long* keys = (unsigned long long*)d_ws;            // 4 MiB
  unsigned short* wbf = (unsigned short*)((char*)d_ws + WBF_OFF);  // 432 KiB
  unsigned short* wpb = wbf + 3 * 256 * KP;
  unsigned short* ftr = (unsigned short*)((char*)d_ws + FTR_OFF);  // 64 MiB
  const int use_tr = (ws_size >= (size_t)FTR_OFF + FTR_BYTES) ? 1 : 0;

  // host-side split of jax.random.key(7) = (0,7): key_i = tf(key, (0,i))
  uint32_t k1a, k1b, k2a, k2b;
  tf2x32(0u, 7u, 0u, 0u, &k1a, &k1b);
  tf2x32(0u, 7u, 0u, 1u, &k2a, &k2b);

  hipMemcpyAsync(out0, coarse, 622592 * sizeof(float),
                 hipMemcpyDeviceToDevice, stream);

  // transpose || uncertainty+RNG || weight-convert in one dispatch
  fusedA<<<11140, 256, 0, stream>>>(feats, ftr, coarse, keys,
                                    w0, w1, w2, wp, wbf, wpb, k1a, k1b, use_tr);

  bitonic_local<<<64, 1024, 0, stream>>>(keys);
  bitonic_global<<<1024, 256, 0, stream>>>(keys, 16384, 8192, 15);
  bitonic_finish<<<64, 1024, 0, stream>>>(keys, 16384);
  bitonic_global<<<1024, 256, 0, stream>>>(keys, 32768, 16384, 15);
  bitonic_global<<<1024, 256, 0, stream>>>(keys, 32768, 8192, 15);
  bitonic_finish<<<64, 1024, 0, stream>>>(keys, 32768);
  // k=65536 tail: only the lowest 16K per batch feed coords.
  bitonic_global<<<1024, 256, 0, stream>>>(keys, 65536, 32768, 15);  // full
  bitonic_global<<<512, 256, 0, stream>>>(keys, 65536, 16384, 14);   // low half
  bitonic_global<<<256, 256, 0, stream>>>(keys, 65536, 8192, 13);    // low quarter
  finlow_coords<<<16, 1024, 0, stream>>>(keys, outC, k1a, k1b, k2a, k2b);

  if (use_tr)
    fused_mfma<1><<<2048, 512, 0, stream>>>(coarse, feats, ftr, b0, b1, b2, bp,
                                            wbf, wpb, outC, outL);
  else
    fused_mfma<0><<<2048, 512, 0, stream>>>(coarse, feats, ftr, b0, b1, b2, bp,
                                            wbf, wpb, outC, outL);
}